// Round 9
// baseline (635.696 us; speedup 1.0000x reference)
//
#include <hip/hip_runtime.h>

namespace {

constexpr int kN = 50000, kE = 200000, kG = 500;
constexpr float kEps = 1e-5f;
constexpr int kNB = (kN + 255) / 256;   // 196 node chunks
constexpr int kEB = (kE + 255) / 256;   // 782 edge chunks

typedef short v8s __attribute__((ext_vector_type(8)));
typedef float v4f __attribute__((ext_vector_type(4)));

__device__ __forceinline__ unsigned short bf16rn(float x) {
    unsigned u = __float_as_uint(x);
    return (unsigned short)((u + 0x7FFFu + ((u >> 16) & 1u)) >> 16);
}
__device__ __forceinline__ float bf16lo(unsigned p) { return __uint_as_float(p << 16); }
__device__ __forceinline__ float bf16hi(unsigned p) { return __uint_as_float(p & 0xFFFF0000u); }
__device__ __forceinline__ unsigned pk2(float a, float b) {
    return (unsigned)bf16rn(a) | ((unsigned)bf16rn(b) << 16);
}

// ---- h16 = leaky(x @ lin_W + lin_b), bf16 [n][c] packed dwords. ----
__global__ __launch_bounds__(1024) void init_h(
    const float* __restrict__ x, const float* __restrict__ W,
    const float* __restrict__ b, unsigned short* __restrict__ h16)
{
    __shared__ unsigned short sx[256 * 96];   // [node][feat pad96]
    __shared__ unsigned short sW[32 * 96];    // [c][feat pad96]
    int t = threadIdx.x;
    for (int i = t; i < 256 * 96; i += 1024) sx[i] = 0;
    for (int i = t; i < 32 * 96; i += 1024) sW[i] = 0;
    __syncthreads();
    int tb = blockIdx.x * 256;
    int cnt = min(256, kN - tb);
    for (int i = t; i < cnt * 75; i += 1024) {
        int n = i / 75, f = i - n * 75;
        sx[n * 96 + f] = bf16rn(x[(size_t)tb * 75 + i]);
    }
    for (int i = t; i < 75 * 32; i += 1024) {
        int f = i >> 5, c = i & 31;
        sW[c * 96 + f] = bf16rn(W[i]);
    }
    __syncthreads();
    int l15 = t & 15, quad = (t >> 4) & 3, w = t >> 6;
    int n = tb + w * 16 + l15;
    unsigned* H = (unsigned*)h16;
    #pragma unroll
    for (int tile = 0; tile < 2; ++tile) {
        v4f acc = {0.f, 0.f, 0.f, 0.f};
        #pragma unroll
        for (int kc = 0; kc < 3; ++kc) {
            v8s a  = *(const v8s*)&sW[(tile * 16 + l15) * 96 + kc * 32 + quad * 8];
            v8s bb = *(const v8s*)&sx[(w * 16 + l15) * 96 + kc * 32 + quad * 8];
            acc = __builtin_amdgcn_mfma_f32_16x16x32_bf16(a, bb, acc, 0, 0, 0);
        }
        if (n < kN) {
            int c0 = tile * 16 + quad * 4;
            float v0 = acc[0] + b[c0],     v1 = acc[1] + b[c0 + 1];
            float v2 = acc[2] + b[c0 + 2], v3 = acc[3] + b[c0 + 3];
            v0 = v0 > 0.f ? v0 : 0.01f * v0;  v1 = v1 > 0.f ? v1 : 0.01f * v1;
            v2 = v2 > 0.f ? v2 : 0.01f * v2;  v3 = v3 > 0.f ? v3 : 0.01f * v3;
            H[n * 16 + (c0 >> 1)]     = pk2(v0, v1);
            H[n * 16 + (c0 >> 1) + 1] = pk2(v2, v3);
        }
    }
}

// ---- hid = relu(ea@W1+b1) for 3 layers, edge order:
// hq[l][e] = {h01, h23, h4 | src<<16, dst}   (kN < 65536 so src fits u16). ----
__global__ __launch_bounds__(256) void hid_pre(
    const float* __restrict__ ea, const float* __restrict__ W1,
    const float* __restrict__ b1, const int* __restrict__ ei,
    uint4* __restrict__ hq)
{
    __shared__ float sE[256 * 13];
    __shared__ float sW[195];
    int t = threadIdx.x;
    for (int i = t; i < 195; i += 256) sW[i] = (i < 180) ? W1[i] : b1[i - 180];
    int base = blockIdx.x * 256;
    int cnt = min(256, kE - base);
    for (int i = t; i < cnt * 12; i += 256) {
        int el = i / 12, f = i - el * 12;
        sE[el * 13 + f] = ea[(size_t)base * 12 + i];
    }
    __syncthreads();
    if (t >= cnt) return;
    int e = base + t;
    unsigned src = (unsigned)ei[e];
    unsigned dst = (unsigned)ei[kE + e];
    float ef[12];
    #pragma unroll
    for (int j = 0; j < 12; ++j) ef[j] = sE[t * 13 + j];
    #pragma unroll
    for (int l = 0; l < 3; ++l) {
        float h[5];
        #pragma unroll
        for (int k = 0; k < 5; ++k) h[k] = sW[180 + l * 5 + k];
        #pragma unroll
        for (int f = 0; f < 12; ++f)
            #pragma unroll
            for (int k = 0; k < 5; ++k)
                h[k] = fmaf(ef[f], sW[l * 60 + f * 5 + k], h[k]);
        #pragma unroll
        for (int k = 0; k < 5; ++k) h[k] = h[k] > 0.f ? h[k] : 0.f;
        hq[(size_t)l * kE + e] = make_uint4(
            pk2(h[0], h[1]), pk2(h[2], h[3]),
            (unsigned)bf16rn(h[4]) | (src << 16), dst);
    }
}

// ---- norm_root: (BN prev + leaky -> h16) fused with obuf = h @ rootW + cb.
// first=1: h16 already valid (from init_h); just root MFMA. ----
__global__ __launch_bounds__(256) void norm_root(
    const float* __restrict__ obuf_prev, unsigned short* __restrict__ h16,
    float* __restrict__ obuf,
    const float* __restrict__ rW, const float* __restrict__ convb,
    const float* __restrict__ statsR,   // 8 replicas x 64 (prev layer)
    const float* __restrict__ gPrev, const float* __restrict__ bPrev,
    int first)
{
    __shared__ unsigned short sh[256 * 32];   // [node][c]
    __shared__ unsigned short sR[32 * 32];    // [d][c]
    int t = threadIdx.x;
    int tb = blockIdx.x * 256;
    int cnt = min(256, kN - tb);
    for (int i = t; i < 1024; i += 256) {
        int d = i >> 5, c = i & 31;
        sR[d * 32 + c] = bf16rn(rW[c * 32 + d]);
    }
    if (first) {
        #pragma unroll
        for (int j = 0; j < 4; ++j) {
            int i4 = t + j * 256;                // 1024 uint4 = 256 rows x 64B
            int nl = i4 >> 2, part = i4 & 3;
            uint4 v = make_uint4(0, 0, 0, 0);
            if (nl < cnt)
                v = ((const uint4*)(h16 + (size_t)(tb + nl) * 32))[part];
            ((uint4*)sh)[i4] = v;
        }
    } else {
        int c = t & 31;
        float sum = 0.f, sq = 0.f;
        #pragma unroll
        for (int r = 0; r < 8; ++r) {
            sum += statsR[r * 64 + c];
            sq  += statsR[r * 64 + 32 + c];
        }
        float mu = sum * (1.f / kN);
        float var = sq * (1.f / kN) - mu * mu;
        float ivg = rsqrtf(var + kEps) * gPrev[c];
        float bb = bPrev[c];
        for (int j = 0; j < 32; ++j) {
            int idx = t + j * 256;
            int nl = idx >> 5;
            float v = 0.f;
            if (nl < cnt) {
                float o = obuf_prev[(size_t)(tb + nl) * 32 + c];
                v = (o - mu) * ivg + bb;
                v = v > 0.f ? v : 0.01f * v;
                h16[(size_t)(tb + nl) * 32 + c] = bf16rn(v);
            }
            sh[idx] = bf16rn(v);
        }
    }
    __syncthreads();
    int l15 = t & 15, quad = (t >> 4) & 3, w = t >> 6;
    #pragma unroll
    for (int jt = 0; jt < 4; ++jt) {
        int nl = w * 64 + jt * 16 + l15;
        v8s bfrag = *(const v8s*)&sh[nl * 32 + quad * 8];
        #pragma unroll
        for (int i = 0; i < 2; ++i) {
            v8s a = *(const v8s*)&sR[(i * 16 + l15) * 32 + quad * 8];
            v4f acc = {0.f, 0.f, 0.f, 0.f};
            acc = __builtin_amdgcn_mfma_f32_16x16x32_bf16(a, bfrag, acc, 0, 0, 0);
            if (nl < cnt) {
                #pragma unroll
                for (int r = 0; r < 4; ++r) {
                    int d = i * 16 + quad * 4 + r;
                    obuf[(size_t)(tb + nl) * 32 + d] = acc[r] + convb[d];
                }
            }
        }
    }
}

// ---- edge_mfma: per 256-edge tile, gather h_src rows (64B each) into LDS,
// MFMA A={W2_k,B2}(k-major co=k*32+d) x B=h_src -> y[k,d] per edge in regs,
// combine with hid, atomic-scatter 32 ch into obuf[dst]. Zeroes stats[l]. ----
__global__ __launch_bounds__(256) void edge_mfma(
    const uint4* __restrict__ hq, const unsigned short* __restrict__ h16,
    const float* __restrict__ W2, const float* __restrict__ b2,
    float* __restrict__ obuf, float* __restrict__ statsL)
{
    __shared__ unsigned short sB[192 * 32];   // [co=k*32+d][c]
    __shared__ unsigned short sh[256 * 32];   // [edge][c]
    __shared__ uint4 sq[256];
    int t = threadIdx.x;
    if (blockIdx.x == 0)
        for (int i = t; i < 512; i += 256) statsL[i] = 0.f;
    int base = blockIdx.x * 256;
    int cnt = min(256, kE - base);
    for (int i = t; i < 192 * 32; i += 256) {
        int co = i >> 5, c = i & 31, k = co >> 5, d = co & 31;
        float v = (k < 5) ? W2[k * 1024 + c * 32 + d] : b2[c * 32 + d];
        sB[co * 32 + c] = bf16rn(v);
    }
    sq[t] = (t < cnt) ? hq[base + t] : make_uint4(0, 0, 0, 0);
    __syncthreads();
    #pragma unroll
    for (int pass = 0; pass < 4; ++pass) {
        int e = pass * 64 + (t >> 2);
        int l4 = t & 3;
        uint4 v = make_uint4(0, 0, 0, 0);
        if (e < cnt) {
            unsigned src = sq[e].z >> 16;
            v = ((const uint4*)(h16 + (size_t)src * 32))[l4];
        }
        ((uint4*)(sh + e * 32))[l4] = v;
    }
    __syncthreads();
    int l15 = t & 15, quad = (t >> 4) & 3, w = t >> 6;
    #pragma unroll 2
    for (int jt = 0; jt < 4; ++jt) {
        int el = w * 64 + jt * 16 + l15;
        uint4 qq = sq[el];
        float hk[6];
        hk[0] = bf16lo(qq.x); hk[1] = bf16hi(qq.x);
        hk[2] = bf16lo(qq.y); hk[3] = bf16hi(qq.y);
        hk[4] = bf16lo(qq.z); hk[5] = 1.f;
        int dst = (int)qq.w;
        v8s bfrag = *(const v8s*)&sh[el * 32 + quad * 8];
        float macc[2][4] = {{0.f,0.f,0.f,0.f},{0.f,0.f,0.f,0.f}};
        #pragma unroll
        for (int i = 0; i < 12; ++i) {
            v8s a = *(const v8s*)&sB[(i * 16 + l15) * 32 + quad * 8];
            v4f acc = {0.f, 0.f, 0.f, 0.f};
            acc = __builtin_amdgcn_mfma_f32_16x16x32_bf16(a, bfrag, acc, 0, 0, 0);
            float hv = hk[i >> 1];
            int half = i & 1;
            #pragma unroll
            for (int r = 0; r < 4; ++r)
                macc[half][r] = fmaf(hv, acc[r], macc[half][r]);
        }
        #pragma unroll
        for (int half = 0; half < 2; ++half)
            #pragma unroll
            for (int r = 0; r < 4; ++r) {
                int d = half * 16 + quad * 4 + r;
                atomicAdd(&obuf[(size_t)dst * 32 + d], macc[half][r]);
            }
    }
}

// ---- BN stats into 8 replica buffers. ----
__global__ __launch_bounds__(256) void bn_reduce(
    const float* __restrict__ obuf, float* __restrict__ statsR)
{
    __shared__ float ls[256];
    __shared__ float lq[256];
    int t = threadIdx.x;
    int c = t & 31, row = t >> 5;
    float s = 0.f, q = 0.f;
    for (int n = blockIdx.x * 8 + row; n < kN; n += gridDim.x * 8) {
        float v = obuf[(size_t)n * 32 + c];
        s += v; q += v * v;
    }
    ls[t] = s; lq[t] = q;
    __syncthreads();
    if (t < 128) { ls[t] += ls[t + 128]; lq[t] += lq[t + 128]; }
    __syncthreads();
    if (t < 64) { ls[t] += ls[t + 64]; lq[t] += lq[t + 64]; }
    __syncthreads();
    if (t < 32) {
        float* rep = statsR + (blockIdx.x & 7) * 64;
        atomicAdd(&rep[t], ls[t] + ls[t + 32]);
        atomicAdd(&rep[32 + t], lq[t] + lq[t + 32]);
    }
}

// ---- final BN + prediction dot -> vbuf; init out with pred_b. ----
__global__ __launch_bounds__(256) void bn_norm_final(
    const float* __restrict__ obuf, const float* __restrict__ statsR,
    const float* __restrict__ g, const float* __restrict__ b,
    float* __restrict__ vbuf, const float* __restrict__ predW,
    float* __restrict__ out, const float* __restrict__ pred_b)
{
    int idx = blockIdx.x * 256 + threadIdx.x;
    if (idx < kG) out[idx] = pred_b[0];
    if (idx >= kN * 32) return;
    int c = idx & 31;
    float sum = 0.f, sq = 0.f;
    #pragma unroll
    for (int r = 0; r < 8; ++r) {
        sum += statsR[r * 64 + c];
        sq  += statsR[r * 64 + 32 + c];
    }
    float mu = sum * (1.f / kN);
    float var = sq * (1.f / kN) - mu * mu;
    float inv = rsqrtf(var + kEps);
    float v = (obuf[idx] - mu) * inv * g[c] + b[c];
    float pv = v * predW[c];
    #pragma unroll
    for (int off = 16; off > 0; off >>= 1) pv += __shfl_down(pv, off, 32);
    if (c == 0) vbuf[idx >> 5] = pv;
}

// ---- segment readout over sorted batch ids. ----
__global__ __launch_bounds__(256) void seg_readout(
    const float* __restrict__ vbuf, const int* __restrict__ batch,
    float* __restrict__ out)
{
    __shared__ float ls[kG];
    int t = threadIdx.x;
    for (int i = t; i < kG; i += 256) ls[i] = 0.f;
    __syncthreads();
    int base = blockIdx.x * 2048 + t * 8;
    int cur = -1; float acc = 0.f;
    #pragma unroll
    for (int i = 0; i < 8; ++i) {
        int n = base + i;
        if (n >= kN) break;
        int gi = batch[n];
        float val = vbuf[n];
        if (gi != cur) {
            if (cur >= 0) atomicAdd(&ls[cur], acc);
            cur = gi; acc = val;
        } else acc += val;
    }
    if (cur >= 0) atomicAdd(&ls[cur], acc);
    __syncthreads();
    for (int i = t; i < kG; i += 256) {
        float s = ls[i];
        if (s != 0.f) atomicAdd(&out[i], s);
    }
}

} // namespace

extern "C" void kernel_launch(void* const* d_in, const int* in_sizes, int n_in,
                              void* d_out, int out_size, void* d_ws, size_t ws_size,
                              hipStream_t stream)
{
    const float* x      = (const float*)d_in[0];
    const int*   ei     = (const int*)d_in[1];
    const float* ea     = (const float*)d_in[2];
    const int*   batch  = (const int*)d_in[3];
    const float* lin_W  = (const float*)d_in[4];
    const float* lin_b  = (const float*)d_in[5];
    const float* mes_W1 = (const float*)d_in[6];
    const float* mes_b1 = (const float*)d_in[7];
    const float* mes_W2 = (const float*)d_in[8];
    const float* mes_b2 = (const float*)d_in[9];
    const float* root_W = (const float*)d_in[10];
    const float* conv_b = (const float*)d_in[11];
    const float* bn_g   = (const float*)d_in[12];
    const float* bn_b   = (const float*)d_in[13];
    const float* pred_W = (const float*)d_in[14];
    const float* pred_b = (const float*)d_in[15];
    float* out = (float*)d_out;

    // ws: stats[3*512 f] | h16[N*32 us] | obuf[N*32 f] | hq[3*E uint4]
    // vbuf[N f] overlays h16 (dead after last edge_mfma).
    char* wsb = (char*)d_ws;
    float* stats = (float*)wsb;                         // 1536 floats (8 KB pad)
    unsigned short* h16 = (unsigned short*)(wsb + 8192);
    float* obuf = (float*)(h16 + (size_t)kN * 32);
    uint4* hq   = (uint4*)(obuf + (size_t)kN * 32);
    float* vbuf = (float*)h16;

    init_h<<<kNB, 1024, 0, stream>>>(x, lin_W, lin_b, h16);
    hid_pre<<<kEB, 256, 0, stream>>>(ea, mes_W1, mes_b1, ei, hq);

    for (int l = 0; l < 3; ++l) {
        norm_root<<<kNB, 256, 0, stream>>>(
            obuf, h16, obuf, root_W + (size_t)l * 1024, conv_b + l * 32,
            stats + (l ? (l - 1) * 512 : 0),
            bn_g + (l ? (l - 1) * 32 : 0), bn_b + (l ? (l - 1) * 32 : 0),
            l == 0 ? 1 : 0);
        edge_mfma<<<kEB, 256, 0, stream>>>(
            hq + (size_t)l * kE, h16,
            mes_W2 + (size_t)l * 5120, mes_b2 + (size_t)l * 1024,
            obuf, stats + l * 512);
        bn_reduce<<<512, 256, 0, stream>>>(obuf, stats + l * 512);
    }

    bn_norm_final<<<(kN * 32 + 255) / 256, 256, 0, stream>>>(
        obuf, stats + 2 * 512, bn_g + 64, bn_b + 64, vbuf, pred_W, out, pred_b);
    seg_readout<<<(kN + 2047) / 2048, 256, 0, stream>>>(vbuf, batch, out);
}

// Round 10
// 335.445 us; speedup vs baseline: 1.8951x; 1.8951x over previous
//
#include <hip/hip_runtime.h>

namespace {

constexpr int kN = 50000, kE = 200000, kG = 500;
constexpr float kEps = 1e-5f;
constexpr int kNB = (kN + 255) / 256;   // 196 node chunks
constexpr int kEB = (kE + 255) / 256;   // 782 edge chunks

typedef short v8s __attribute__((ext_vector_type(8)));
typedef float v4f __attribute__((ext_vector_type(4)));

__device__ __forceinline__ unsigned short bf16rn(float x) {
    unsigned u = __float_as_uint(x);
    return (unsigned short)((u + 0x7FFFu + ((u >> 16) & 1u)) >> 16);
}
__device__ __forceinline__ float bf16lo(unsigned p) { return __uint_as_float(p << 16); }
__device__ __forceinline__ float bf16hi(unsigned p) { return __uint_as_float(p & 0xFFFF0000u); }
__device__ __forceinline__ unsigned pk2(float a, float b) {
    return (unsigned)bf16rn(a) | ((unsigned)bf16rn(b) << 16);
}

// ---- zero deg + stats. ----
__global__ __launch_bounds__(256) void zero_init(int* __restrict__ deg,
                                                 float* __restrict__ stats) {
    int i = blockIdx.x * 256 + threadIdx.x;
    if (i < kN) deg[i] = 0;
    if (i < 1536) stats[i] = 0.f;   // 3 layers x 8 replicas x 64
}

// ---- degree histogram by dst. ----
__global__ __launch_bounds__(256) void deg_hist(
    const int* __restrict__ ei, int* __restrict__ deg)
{
    int e = blockIdx.x * 256 + threadIdx.x;
    if (e < kE) atomicAdd(&deg[ei[kE + e]], 1);
}

// ---- h16 = leaky(x @ lin_W + lin_b), bf16 [n][c] packed dwords. ----
__global__ __launch_bounds__(1024) void init_h(
    const float* __restrict__ x, const float* __restrict__ W,
    const float* __restrict__ b, unsigned short* __restrict__ h16)
{
    __shared__ unsigned short sx[256 * 96];
    __shared__ unsigned short sW[32 * 96];
    int t = threadIdx.x;
    for (int i = t; i < 256 * 96; i += 1024) sx[i] = 0;
    for (int i = t; i < 32 * 96; i += 1024) sW[i] = 0;
    __syncthreads();
    int tb = blockIdx.x * 256;
    int cnt = min(256, kN - tb);
    for (int i = t; i < cnt * 75; i += 1024) {
        int n = i / 75, f = i - n * 75;
        sx[n * 96 + f] = bf16rn(x[(size_t)tb * 75 + i]);
    }
    for (int i = t; i < 75 * 32; i += 1024) {
        int f = i >> 5, c = i & 31;
        sW[c * 96 + f] = bf16rn(W[i]);
    }
    __syncthreads();
    int l15 = t & 15, quad = (t >> 4) & 3, w = t >> 6;
    int n = tb + w * 16 + l15;
    unsigned* H = (unsigned*)h16;
    #pragma unroll
    for (int tile = 0; tile < 2; ++tile) {
        v4f acc = {0.f, 0.f, 0.f, 0.f};
        #pragma unroll
        for (int kc = 0; kc < 3; ++kc) {
            v8s a  = *(const v8s*)&sW[(tile * 16 + l15) * 96 + kc * 32 + quad * 8];
            v8s bb = *(const v8s*)&sx[(w * 16 + l15) * 96 + kc * 32 + quad * 8];
            acc = __builtin_amdgcn_mfma_f32_16x16x32_bf16(a, bb, acc, 0, 0, 0);
        }
        if (n < kN) {
            int c0 = tile * 16 + quad * 4;
            float v0 = acc[0] + b[c0],     v1 = acc[1] + b[c0 + 1];
            float v2 = acc[2] + b[c0 + 2], v3 = acc[3] + b[c0 + 3];
            v0 = v0 > 0.f ? v0 : 0.01f * v0;  v1 = v1 > 0.f ? v1 : 0.01f * v1;
            v2 = v2 > 0.f ? v2 : 0.01f * v2;  v3 = v3 > 0.f ? v3 : 0.01f * v3;
            H[n * 16 + (c0 >> 1)]     = pk2(v0, v1);
            H[n * 16 + (c0 >> 1) + 1] = pk2(v2, v3);
        }
    }
}

// ---- scan phase 1. ----
__global__ __launch_bounds__(256) void scan_part(
    const int* __restrict__ deg, int* __restrict__ blkSum)
{
    __shared__ int sc[256];
    int t = threadIdx.x;
    int idx = blockIdx.x * 256 + t;
    sc[t] = (idx < kN) ? deg[idx] : 0;
    __syncthreads();
    #pragma unroll
    for (int off = 128; off > 0; off >>= 1) {
        if (t < off) sc[t] += sc[t + off];
        __syncthreads();
    }
    if (t == 0) blkSum[blockIdx.x] = sc[0];
}

// ---- scan phase 2. ----
__global__ __launch_bounds__(256) void scan_top(
    const int* __restrict__ blkSum, int* __restrict__ blkOff)
{
    __shared__ int sc[256];
    int t = threadIdx.x;
    int v = (t < kNB) ? blkSum[t] : 0;
    sc[t] = v;
    __syncthreads();
    #pragma unroll
    for (int off = 1; off < 256; off <<= 1) {
        int u = (t >= off) ? sc[t - off] : 0;
        __syncthreads();
        sc[t] += u;
        __syncthreads();
    }
    if (t < kNB) blkOff[t] = sc[t] - v;
}

// ---- scan phase 3 -> cursor. ----
__global__ __launch_bounds__(256) void scan_add(
    const int* __restrict__ deg, const int* __restrict__ blkOff,
    int* __restrict__ cursor)
{
    __shared__ int sc[256];
    int t = threadIdx.x;
    int idx = blockIdx.x * 256 + t;
    int v = (idx < kN) ? deg[idx] : 0;
    sc[t] = v;
    __syncthreads();
    #pragma unroll
    for (int off = 1; off < 256; off <<= 1) {
        int u = (t >= off) ? sc[t - off] : 0;
        __syncthreads();
        sc[t] += u;
        __syncthreads();
    }
    if (idx < kN) cursor[idx] = blkOff[blockIdx.x] + sc[t] - v;
}

// ---- hid = relu(ea@W1+b1), 3 layers, written into dst-sorted CSR slots:
// hq[l][pos] = {h01, h23, h4 | src<<16, dst}. ----
__global__ __launch_bounds__(256) void hid_pre(
    const float* __restrict__ ea, const float* __restrict__ W1,
    const float* __restrict__ b1, const int* __restrict__ ei,
    int* __restrict__ cursor, uint4* __restrict__ hq)
{
    __shared__ float sE[256 * 13];
    __shared__ float sW[195];
    int t = threadIdx.x;
    for (int i = t; i < 195; i += 256) sW[i] = (i < 180) ? W1[i] : b1[i - 180];
    int base = blockIdx.x * 256;
    int cnt = min(256, kE - base);
    for (int i = t; i < cnt * 12; i += 256) {
        int el = i / 12, f = i - el * 12;
        sE[el * 13 + f] = ea[(size_t)base * 12 + i];
    }
    __syncthreads();
    if (t >= cnt) return;
    int e = base + t;
    unsigned src = (unsigned)ei[e];
    unsigned dst = (unsigned)ei[kE + e];
    int pos = atomicAdd(&cursor[dst], 1);
    float ef[12];
    #pragma unroll
    for (int j = 0; j < 12; ++j) ef[j] = sE[t * 13 + j];
    #pragma unroll
    for (int l = 0; l < 3; ++l) {
        float h[5];
        #pragma unroll
        for (int k = 0; k < 5; ++k) h[k] = sW[180 + l * 5 + k];
        #pragma unroll
        for (int f = 0; f < 12; ++f)
            #pragma unroll
            for (int k = 0; k < 5; ++k)
                h[k] = fmaf(ef[f], sW[l * 60 + f * 5 + k], h[k]);
        #pragma unroll
        for (int k = 0; k < 5; ++k) h[k] = h[k] > 0.f ? h[k] : 0.f;
        hq[(size_t)l * kE + pos] = make_uint4(
            pk2(h[0], h[1]), pk2(h[2], h[3]),
            (unsigned)bf16rn(h[4]) | (src << 16), dst);
    }
}

// ---- norm_root (1024 thr): BN(prev)+leaky -> h16, obuf = h @ rootW + cb. ----
__global__ __launch_bounds__(1024) void norm_root(
    unsigned short* __restrict__ h16, float* __restrict__ obuf,
    const float* __restrict__ rW, const float* __restrict__ convb,
    const float* __restrict__ statsR,
    const float* __restrict__ gPrev, const float* __restrict__ bPrev,
    int first)
{
    __shared__ unsigned short sh[256 * 32];
    __shared__ unsigned short sR[32 * 32];
    int t = threadIdx.x;
    int tb = blockIdx.x * 256;
    int cnt = min(256, kN - tb);
    for (int i = t; i < 1024; i += 1024) {
        int d = i >> 5, c = i & 31;
        sR[d * 32 + c] = bf16rn(rW[c * 32 + d]);
    }
    if (first) {
        #pragma unroll
        for (int j = 0; j < 8; ++j) {
            int idx = t + j * 1024;
            int nl = idx >> 5, c = idx & 31;
            sh[idx] = (nl < cnt) ? h16[(size_t)(tb + nl) * 32 + c]
                                 : (unsigned short)0;
        }
    } else {
        int c = t & 31;
        float sum = 0.f, sq = 0.f;
        #pragma unroll
        for (int r = 0; r < 8; ++r) {
            sum += statsR[r * 64 + c];
            sq  += statsR[r * 64 + 32 + c];
        }
        float mu = sum * (1.f / kN);
        float var = sq * (1.f / kN) - mu * mu;
        float ivg = rsqrtf(var + kEps) * gPrev[c];
        float bb = bPrev[c];
        #pragma unroll
        for (int j = 0; j < 8; ++j) {
            int idx = t + j * 1024;
            int nl = idx >> 5;
            float v = 0.f;
            if (nl < cnt) {
                float o = obuf[(size_t)(tb + nl) * 32 + c];
                v = (o - mu) * ivg + bb;
                v = v > 0.f ? v : 0.01f * v;
                h16[(size_t)(tb + nl) * 32 + c] = bf16rn(v);
            }
            sh[idx] = bf16rn(v);
        }
    }
    __syncthreads();
    int l15 = t & 15, quad = (t >> 4) & 3, w = t >> 6;  // 16 waves
    int nl = w * 16 + l15;
    v8s bfrag = *(const v8s*)&sh[nl * 32 + quad * 8];
    #pragma unroll
    for (int i = 0; i < 2; ++i) {
        v8s a = *(const v8s*)&sR[(i * 16 + l15) * 32 + quad * 8];
        v4f acc = {0.f, 0.f, 0.f, 0.f};
        acc = __builtin_amdgcn_mfma_f32_16x16x32_bf16(a, bfrag, acc, 0, 0, 0);
        if (nl < cnt) {
            #pragma unroll
            for (int r = 0; r < 4; ++r) {
                int d = i * 16 + quad * 4 + r;
                obuf[(size_t)(tb + nl) * 32 + d] = acc[r] + convb[d];
            }
        }
    }
}

// ---- edge_agg: per 256-edge (dst-sorted) tile:
// gather h16[src] rows -> LDS, MFMA {W2,B2}@h_src -> msg in regs,
// transpose via LDS to [e][d], run-accumulated lane-coalesced atomic scatter.
__global__ __launch_bounds__(256) void edge_agg(
    const uint4* __restrict__ hq, const unsigned short* __restrict__ h16,
    const float* __restrict__ W2, const float* __restrict__ b2,
    float* __restrict__ obuf)
{
    __shared__ union U {
        struct { unsigned short sB[192 * 32]; unsigned short sh[256 * 32]; } a;
        float smsg[256 * 33];
    } u;
    __shared__ uint4 sq[256];
    int t = threadIdx.x;
    int base = blockIdx.x * 256;
    int cnt = min(256, kE - base);
    for (int i = t; i < 192 * 32; i += 256) {
        int co = i >> 5, c = i & 31, k = co >> 5, d = co & 31;
        float v = (k < 5) ? W2[k * 1024 + c * 32 + d] : b2[c * 32 + d];
        u.a.sB[co * 32 + c] = bf16rn(v);
    }
    sq[t] = (t < cnt) ? hq[base + t] : make_uint4(0, 0, 0, 0);
    __syncthreads();
    #pragma unroll
    for (int pass = 0; pass < 4; ++pass) {
        int e = pass * 64 + (t >> 2);
        int l4 = t & 3;
        uint4 v = make_uint4(0, 0, 0, 0);
        if (e < cnt) {
            unsigned src = sq[e].z >> 16;
            v = ((const uint4*)(h16 + (size_t)src * 32))[l4];
        }
        ((uint4*)(u.a.sh + e * 32))[l4] = v;
    }
    __syncthreads();
    int l15 = t & 15, quad = (t >> 4) & 3, w = t >> 6;
    float macc[4][8];   // [jt][half*4+r]
    #pragma unroll
    for (int jt = 0; jt < 4; ++jt) {
        int el = w * 64 + jt * 16 + l15;
        uint4 qq = sq[el];
        float hk[6];
        hk[0] = bf16lo(qq.x); hk[1] = bf16hi(qq.x);
        hk[2] = bf16lo(qq.y); hk[3] = bf16hi(qq.y);
        hk[4] = bf16lo(qq.z); hk[5] = 1.f;
        v8s bfrag = *(const v8s*)&u.a.sh[el * 32 + quad * 8];
        #pragma unroll
        for (int i = 0; i < 8; ++i) macc[jt][i] = 0.f;
        #pragma unroll
        for (int i = 0; i < 12; ++i) {
            v8s a = *(const v8s*)&u.a.sB[(i * 16 + l15) * 32 + quad * 8];
            v4f acc = {0.f, 0.f, 0.f, 0.f};
            acc = __builtin_amdgcn_mfma_f32_16x16x32_bf16(a, bfrag, acc, 0, 0, 0);
            float hv = hk[i >> 1];
            int half = i & 1;
            #pragma unroll
            for (int r = 0; r < 4; ++r)
                macc[jt][half * 4 + r] = fmaf(hv, acc[r], macc[jt][half * 4 + r]);
        }
    }
    __syncthreads();    // sB/sh dead; overlay smsg
    #pragma unroll
    for (int jt = 0; jt < 4; ++jt) {
        int el = w * 64 + jt * 16 + l15;
        #pragma unroll
        for (int half = 0; half < 2; ++half)
            #pragma unroll
            for (int r = 0; r < 4; ++r)
                u.smsg[el * 33 + half * 16 + quad * 4 + r] = macc[jt][half * 4 + r];
    }
    __syncthreads();
    // scatter: 8 groups x 32 consecutive (dst-sorted) edges, lanes = channels
    int grp = t >> 5, d = t & 31;
    int e0 = grp * 32;
    float acc = 0.f;
    unsigned cur = 0xFFFFFFFFu;
    for (int i = 0; i < 32; ++i) {
        int e = e0 + i;
        if (e >= cnt) break;
        unsigned dst = sq[e].w;
        float val = u.smsg[e * 33 + d];
        if (dst != cur) {
            if (cur != 0xFFFFFFFFu) atomicAdd(&obuf[(size_t)cur * 32 + d], acc);
            cur = dst; acc = val;
        } else acc += val;
    }
    if (cur != 0xFFFFFFFFu) atomicAdd(&obuf[(size_t)cur * 32 + d], acc);
}

// ---- BN stats into 8 replica buffers. ----
__global__ __launch_bounds__(256) void bn_reduce(
    const float* __restrict__ obuf, float* __restrict__ statsR)
{
    __shared__ float ls[256];
    __shared__ float lq[256];
    int t = threadIdx.x;
    int c = t & 31, row = t >> 5;
    float s = 0.f, q = 0.f;
    for (int n = blockIdx.x * 8 + row; n < kN; n += gridDim.x * 8) {
        float v = obuf[(size_t)n * 32 + c];
        s += v; q += v * v;
    }
    ls[t] = s; lq[t] = q;
    __syncthreads();
    if (t < 128) { ls[t] += ls[t + 128]; lq[t] += lq[t + 128]; }
    __syncthreads();
    if (t < 64) { ls[t] += ls[t + 64]; lq[t] += lq[t + 64]; }
    __syncthreads();
    if (t < 32) {
        float* rep = statsR + (blockIdx.x & 7) * 64;
        atomicAdd(&rep[t], ls[t] + ls[t + 32]);
        atomicAdd(&rep[32 + t], lq[t] + lq[t + 32]);
    }
}

// ---- final BN + prediction dot -> vbuf; init out with pred_b. ----
__global__ __launch_bounds__(256) void bn_norm_final(
    const float* __restrict__ obuf, const float* __restrict__ statsR,
    const float* __restrict__ g, const float* __restrict__ b,
    float* __restrict__ vbuf, const float* __restrict__ predW,
    float* __restrict__ out, const float* __restrict__ pred_b)
{
    int idx = blockIdx.x * 256 + threadIdx.x;
    if (idx < kG) out[idx] = pred_b[0];
    if (idx >= kN * 32) return;
    int c = idx & 31;
    float sum = 0.f, sq = 0.f;
    #pragma unroll
    for (int r = 0; r < 8; ++r) {
        sum += statsR[r * 64 + c];
        sq  += statsR[r * 64 + 32 + c];
    }
    float mu = sum * (1.f / kN);
    float var = sq * (1.f / kN) - mu * mu;
    float inv = rsqrtf(var + kEps);
    float v = (obuf[idx] - mu) * inv * g[c] + b[c];
    float pv = v * predW[c];
    #pragma unroll
    for (int off = 16; off > 0; off >>= 1) pv += __shfl_down(pv, off, 32);
    if (c == 0) vbuf[idx >> 5] = pv;
}

// ---- segment readout over sorted batch ids. ----
__global__ __launch_bounds__(256) void seg_readout(
    const float* __restrict__ vbuf, const int* __restrict__ batch,
    float* __restrict__ out)
{
    __shared__ float ls[kG];
    int t = threadIdx.x;
    for (int i = t; i < kG; i += 256) ls[i] = 0.f;
    __syncthreads();
    int base = blockIdx.x * 2048 + t * 8;
    int cur = -1; float acc = 0.f;
    #pragma unroll
    for (int i = 0; i < 8; ++i) {
        int n = base + i;
        if (n >= kN) break;
        int gi = batch[n];
        float val = vbuf[n];
        if (gi != cur) {
            if (cur >= 0) atomicAdd(&ls[cur], acc);
            cur = gi; acc = val;
        } else acc += val;
    }
    if (cur >= 0) atomicAdd(&ls[cur], acc);
    __syncthreads();
    for (int i = t; i < kG; i += 256) {
        float s = ls[i];
        if (s != 0.f) atomicAdd(&out[i], s);
    }
}

} // namespace

extern "C" void kernel_launch(void* const* d_in, const int* in_sizes, int n_in,
                              void* d_out, int out_size, void* d_ws, size_t ws_size,
                              hipStream_t stream)
{
    const float* x      = (const float*)d_in[0];
    const int*   ei     = (const int*)d_in[1];
    const float* ea     = (const float*)d_in[2];
    const int*   batch  = (const int*)d_in[3];
    const float* lin_W  = (const float*)d_in[4];
    const float* lin_b  = (const float*)d_in[5];
    const float* mes_W1 = (const float*)d_in[6];
    const float* mes_b1 = (const float*)d_in[7];
    const float* mes_W2 = (const float*)d_in[8];
    const float* mes_b2 = (const float*)d_in[9];
    const float* root_W = (const float*)d_in[10];
    const float* conv_b = (const float*)d_in[11];
    const float* bn_g   = (const float*)d_in[12];
    const float* bn_b   = (const float*)d_in[13];
    const float* pred_W = (const float*)d_in[14];
    const float* pred_b = (const float*)d_in[15];
    float* out = (float*)d_out;

    // ws: stats[1536 f, 8KB pad] | deg[N] cursor[N] blkSum[256] blkOff[256]
    //     | h16[N*32 us] | obuf[N*32 f] | hq[3*E uint4]
    // vbuf[N f] overlays h16 (dead after last edge_agg).
    char* wsb = (char*)d_ws;
    float* stats = (float*)wsb;
    int* deg     = (int*)(wsb + 8192);
    int* cursor  = deg + kN;
    int* blkSum  = cursor + kN;
    int* blkOff  = blkSum + 256;
    unsigned short* h16 = (unsigned short*)(blkOff + 256);
    float* obuf  = (float*)(h16 + (size_t)kN * 32);
    uint4* hq    = (uint4*)(obuf + (size_t)kN * 32);
    float* vbuf  = (float*)h16;

    zero_init<<<kNB, 256, 0, stream>>>(deg, stats);
    deg_hist<<<kEB, 256, 0, stream>>>(ei, deg);
    init_h<<<kNB, 1024, 0, stream>>>(x, lin_W, lin_b, h16);
    scan_part<<<kNB, 256, 0, stream>>>(deg, blkSum);
    scan_top<<<1, 256, 0, stream>>>(blkSum, blkOff);
    scan_add<<<kNB, 256, 0, stream>>>(deg, blkOff, cursor);
    hid_pre<<<kEB, 256, 0, stream>>>(ea, mes_W1, mes_b1, ei, cursor, hq);

    for (int l = 0; l < 3; ++l) {
        norm_root<<<kNB, 1024, 0, stream>>>(
            h16, obuf, root_W + (size_t)l * 1024, conv_b + l * 32,
            stats + (l ? (l - 1) * 512 : 0),
            bn_g + (l ? (l - 1) * 32 : 0), bn_b + (l ? (l - 1) * 32 : 0),
            l == 0 ? 1 : 0);
        edge_agg<<<kEB, 256, 0, stream>>>(
            hq + (size_t)l * kE, h16,
            mes_W2 + (size_t)l * 5120, mes_b2 + (size_t)l * 1024, obuf);
        bn_reduce<<<512, 256, 0, stream>>>(obuf, stats + l * 512);
    }

    bn_norm_final<<<(kN * 32 + 255) / 256, 256, 0, stream>>>(
        obuf, stats + 2 * 512, bn_g + 64, bn_b + 64, vbuf, pred_W, out, pred_b);
    seg_readout<<<(kN + 2047) / 2048, 256, 0, stream>>>(vbuf, batch, out);
}

// Round 11
// 289.726 us; speedup vs baseline: 2.1941x; 1.1578x over previous
//
#include <hip/hip_runtime.h>

namespace {

constexpr int kN = 50000, kE = 200000, kG = 500;
constexpr float kEps = 1e-5f;
constexpr int kNB = (kN + 255) / 256;   // 196 node chunks
constexpr int kEB = (kE + 255) / 256;   // 782 edge chunks

typedef short v8s __attribute__((ext_vector_type(8)));
typedef float v4f __attribute__((ext_vector_type(4)));

__device__ __forceinline__ unsigned short bf16rn(float x) {
    unsigned u = __float_as_uint(x);
    return (unsigned short)((u + 0x7FFFu + ((u >> 16) & 1u)) >> 16);
}
__device__ __forceinline__ float bf16lo(unsigned p) { return __uint_as_float(p << 16); }
__device__ __forceinline__ float bf16hi(unsigned p) { return __uint_as_float(p & 0xFFFF0000u); }
__device__ __forceinline__ unsigned pk2(float a, float b) {
    return (unsigned)bf16rn(a) | ((unsigned)bf16rn(b) << 16);
}

// ---- zero deg + stats. ----
__global__ __launch_bounds__(256) void zero_init(int* __restrict__ deg,
                                                 float* __restrict__ stats) {
    int i = blockIdx.x * 256 + threadIdx.x;
    if (i < kN) deg[i] = 0;
    if (i < 1536) stats[i] = 0.f;   // 3 layers x 8 replicas x 64
}

// ---- degree histogram by dst. ----
__global__ __launch_bounds__(256) void deg_hist(
    const int* __restrict__ ei, int* __restrict__ deg)
{
    int e = blockIdx.x * 256 + threadIdx.x;
    if (e < kE) atomicAdd(&deg[ei[kE + e]], 1);
}

// ---- h = leaky(x @ lin_W + lin_b), fp32 [n][c], MFMA (A=nodes). ----
__global__ __launch_bounds__(1024) void init_h(
    const float* __restrict__ x, const float* __restrict__ W,
    const float* __restrict__ b, float* __restrict__ hbuf)
{
    __shared__ unsigned short sx[256 * 96];
    __shared__ unsigned short sW[32 * 96];
    int t = threadIdx.x;
    for (int i = t; i < 256 * 96; i += 1024) sx[i] = 0;
    for (int i = t; i < 32 * 96; i += 1024) sW[i] = 0;
    __syncthreads();
    int tb = blockIdx.x * 256;
    int cnt = min(256, kN - tb);
    for (int i = t; i < cnt * 75; i += 1024) {
        int n = i / 75, f = i - n * 75;
        sx[n * 96 + f] = bf16rn(x[(size_t)tb * 75 + i]);
    }
    for (int i = t; i < 75 * 32; i += 1024) {
        int f = i >> 5, c = i & 31;
        sW[c * 96 + f] = bf16rn(W[i]);
    }
    __syncthreads();
    int l15 = t & 15, quad = (t >> 4) & 3, w = t >> 6;
    #pragma unroll
    for (int tile = 0; tile < 2; ++tile) {
        v4f acc = {0.f, 0.f, 0.f, 0.f};
        #pragma unroll
        for (int kc = 0; kc < 3; ++kc) {
            v8s a  = *(const v8s*)&sx[(w * 16 + l15) * 96 + kc * 32 + quad * 8];
            v8s bb = *(const v8s*)&sW[(tile * 16 + l15) * 96 + kc * 32 + quad * 8];
            acc = __builtin_amdgcn_mfma_f32_16x16x32_bf16(a, bb, acc, 0, 0, 0);
        }
        int c = tile * 16 + l15;
        float bc = b[c];
        #pragma unroll
        for (int r = 0; r < 4; ++r) {
            int n = tb + w * 16 + quad * 4 + r;
            if (n < kN) {
                float v = acc[r] + bc;
                hbuf[(size_t)n * 32 + c] = v > 0.f ? v : 0.01f * v;
            }
        }
    }
}

// ---- scan phase 1. ----
__global__ __launch_bounds__(256) void scan_part(
    const int* __restrict__ deg, int* __restrict__ blkSum)
{
    __shared__ int sc[256];
    int t = threadIdx.x;
    int idx = blockIdx.x * 256 + t;
    sc[t] = (idx < kN) ? deg[idx] : 0;
    __syncthreads();
    #pragma unroll
    for (int off = 128; off > 0; off >>= 1) {
        if (t < off) sc[t] += sc[t + off];
        __syncthreads();
    }
    if (t == 0) blkSum[blockIdx.x] = sc[0];
}

// ---- scan phase 2. ----
__global__ __launch_bounds__(256) void scan_top(
    const int* __restrict__ blkSum, int* __restrict__ blkOff)
{
    __shared__ int sc[256];
    int t = threadIdx.x;
    int v = (t < kNB) ? blkSum[t] : 0;
    sc[t] = v;
    __syncthreads();
    #pragma unroll
    for (int off = 1; off < 256; off <<= 1) {
        int u = (t >= off) ? sc[t - off] : 0;
        __syncthreads();
        sc[t] += u;
        __syncthreads();
    }
    if (t < kNB) blkOff[t] = sc[t] - v;
}

// ---- scan phase 3 -> cursor. ----
__global__ __launch_bounds__(256) void scan_add(
    const int* __restrict__ deg, const int* __restrict__ blkOff,
    int* __restrict__ cursor)
{
    __shared__ int sc[256];
    int t = threadIdx.x;
    int idx = blockIdx.x * 256 + t;
    int v = (idx < kN) ? deg[idx] : 0;
    sc[t] = v;
    __syncthreads();
    #pragma unroll
    for (int off = 1; off < 256; off <<= 1) {
        int u = (t >= off) ? sc[t - off] : 0;
        __syncthreads();
        sc[t] += u;
        __syncthreads();
    }
    if (idx < kN) cursor[idx] = blkOff[blockIdx.x] + sc[t] - v;
}

// ---- hid = relu(ea@W1+b1), 3 layers, into dst-sorted CSR slots:
// hq[l][pos] = {h01, h23, h4 | src<<16, dst}. ----
__global__ __launch_bounds__(256) void hid_pre(
    const float* __restrict__ ea, const float* __restrict__ W1,
    const float* __restrict__ b1, const int* __restrict__ ei,
    int* __restrict__ cursor, uint4* __restrict__ hq)
{
    __shared__ float sE[256 * 13];
    __shared__ float sW[195];
    int t = threadIdx.x;
    for (int i = t; i < 195; i += 256) sW[i] = (i < 180) ? W1[i] : b1[i - 180];
    int base = blockIdx.x * 256;
    int cnt = min(256, kE - base);
    for (int i = t; i < cnt * 12; i += 256) {
        int el = i / 12, f = i - el * 12;
        sE[el * 13 + f] = ea[(size_t)base * 12 + i];
    }
    __syncthreads();
    if (t >= cnt) return;
    int e = base + t;
    unsigned src = (unsigned)ei[e];
    unsigned dst = (unsigned)ei[kE + e];
    int pos = atomicAdd(&cursor[dst], 1);
    float ef[12];
    #pragma unroll
    for (int j = 0; j < 12; ++j) ef[j] = sE[t * 13 + j];
    #pragma unroll
    for (int l = 0; l < 3; ++l) {
        float h[5];
        #pragma unroll
        for (int k = 0; k < 5; ++k) h[k] = sW[180 + l * 5 + k];
        #pragma unroll
        for (int f = 0; f < 12; ++f)
            #pragma unroll
            for (int k = 0; k < 5; ++k)
                h[k] = fmaf(ef[f], sW[l * 60 + f * 5 + k], h[k]);
        #pragma unroll
        for (int k = 0; k < 5; ++k) h[k] = h[k] > 0.f ? h[k] : 0.f;
        hq[(size_t)l * kE + pos] = make_uint4(
            pk2(h[0], h[1]), pk2(h[2], h[3]),
            (unsigned)bf16rn(h[4]) | (src << 16), dst);
    }
}

// ---- y_root MFMA (A=weights co=d*8+k, B=nodes): packed bf16 dword stores
// into Y [n][d][k0..7]us; k==6 -> obuf = root + conv_b. BN prev fused. ----
__global__ __launch_bounds__(1024) void y_root(
    const float* __restrict__ hbuf, float* __restrict__ obuf,
    const float* __restrict__ W2, const float* __restrict__ b2,
    const float* __restrict__ rW, const float* __restrict__ convb,
    const float* __restrict__ statsR,
    const float* __restrict__ gPrev, const float* __restrict__ bPrev,
    int first, unsigned* __restrict__ Ydw)
{
    __shared__ unsigned short sh[256 * 32];
    __shared__ unsigned short sB[256 * 32];
    int t = threadIdx.x;
    int tb = blockIdx.x * 256;
    int cnt = min(256, kN - tb);
    for (int i = t; i < 8192; i += 1024) {
        int co = i >> 5, c = i & 31, d = co >> 3, k = co & 7;
        float v = (k < 5) ? W2[k * 1024 + c * 32 + d]
                : (k == 5) ? b2[c * 32 + d]
                : (k == 6) ? rW[c * 32 + d] : 0.f;
        sB[co * 32 + c] = bf16rn(v);
    }
    if (first) {
        #pragma unroll
        for (int j = 0; j < 8; ++j) {
            int idx = t + j * 1024;
            int nl = idx >> 5, c = idx & 31;
            float v = (nl < cnt) ? hbuf[(size_t)(tb + nl) * 32 + c] : 0.f;
            sh[idx] = bf16rn(v);
        }
    } else {
        int c = t & 31;
        float sum = 0.f, sq = 0.f;
        #pragma unroll
        for (int r = 0; r < 8; ++r) {
            sum += statsR[r * 64 + c];
            sq  += statsR[r * 64 + 32 + c];
        }
        float mu = sum * (1.f / kN);
        float var = sq * (1.f / kN) - mu * mu;
        float ivg = rsqrtf(var + kEps) * gPrev[c];
        float bb = bPrev[c];
        #pragma unroll
        for (int j = 0; j < 8; ++j) {
            int idx = t + j * 1024;
            int nl = idx >> 5;
            float v = 0.f;
            if (nl < cnt) {
                float o = obuf[(size_t)(tb + nl) * 32 + c];
                v = (o - mu) * ivg + bb;
                v = v > 0.f ? v : 0.01f * v;
            }
            sh[idx] = bf16rn(v);
        }
    }
    __syncthreads();
    int l15 = t & 15, quad = (t >> 4) & 3, w = t >> 6;
    int n = tb + w * 16 + l15;
    v8s bn_ = *(const v8s*)&sh[(w * 16 + l15) * 32 + quad * 8];
    #pragma unroll
    for (int i = 0; i < 16; ++i) {
        v8s a = *(const v8s*)&sB[(i * 16 + l15) * 32 + quad * 8];
        v4f acc = {0.f, 0.f, 0.f, 0.f};
        acc = __builtin_amdgcn_mfma_f32_16x16x32_bf16(a, bn_, acc, 0, 0, 0);
        if (n < kN) {
            int cb = i * 16 + quad * 4;
            int d = cb >> 3, koff = cb & 7;
            if (koff == 0) {
                Ydw[(size_t)n * 128 + d * 4]     = pk2(acc[0], acc[1]); // k0,k1
                Ydw[(size_t)n * 128 + d * 4 + 1] = pk2(acc[2], acc[3]); // k2,k3
            } else {
                Ydw[(size_t)n * 128 + d * 4 + 2] = pk2(acc[0], acc[1]); // k4,k5
                obuf[(size_t)n * 32 + d] = acc[2] + convb[d];           // k6
            }
        }
    }
}

// ---- edge_scat: edge-parallel over dst-sorted hq. 32 lanes = channels,
// each group walks 16 consecutive edges: 1 broadcast hq uint4 + 1 Y uint4
// gather + 5 FMA; register run-accumulation -> lane-coalesced atomic per
// dst-run. No LDS, no barriers; max wave-parallelism. ----
__global__ __launch_bounds__(256) void edge_scat(
    const uint4* __restrict__ hq, const unsigned short* __restrict__ Yus,
    float* __restrict__ obuf)
{
    int gid = blockIdx.x * 256 + threadIdx.x;
    int grp = gid >> 5;
    if (grp >= kE / 16) return;
    int d = gid & 31;
    int e0 = grp * 16;
    float acc = 0.f;
    unsigned cur = 0xFFFFFFFFu;
    #pragma unroll 4
    for (int i = 0; i < 16; ++i) {
        uint4 q = hq[e0 + i];
        unsigned src = q.z >> 16;
        uint4 p = *(const uint4*)(Yus + (size_t)src * 256 + d * 8);
        float m = bf16hi(p.z);                       // k5 bias-matrix term
        m = fmaf(bf16lo(q.x), bf16lo(p.x), m);
        m = fmaf(bf16hi(q.x), bf16hi(p.x), m);
        m = fmaf(bf16lo(q.y), bf16lo(p.y), m);
        m = fmaf(bf16hi(q.y), bf16hi(p.y), m);
        m = fmaf(bf16lo(q.z), bf16lo(p.z), m);
        if (q.w != cur) {
            if (cur != 0xFFFFFFFFu) atomicAdd(&obuf[(size_t)cur * 32 + d], acc);
            cur = q.w; acc = m;
        } else acc += m;
    }
    if (cur != 0xFFFFFFFFu) atomicAdd(&obuf[(size_t)cur * 32 + d], acc);
}

// ---- BN stats into 8 replica buffers. ----
__global__ __launch_bounds__(256) void bn_reduce(
    const float* __restrict__ obuf, float* __restrict__ statsR)
{
    __shared__ float ls[256];
    __shared__ float lq[256];
    int t = threadIdx.x;
    int c = t & 31, row = t >> 5;
    float s = 0.f, q = 0.f;
    for (int n = blockIdx.x * 8 + row; n < kN; n += gridDim.x * 8) {
        float v = obuf[(size_t)n * 32 + c];
        s += v; q += v * v;
    }
    ls[t] = s; lq[t] = q;
    __syncthreads();
    if (t < 128) { ls[t] += ls[t + 128]; lq[t] += lq[t + 128]; }
    __syncthreads();
    if (t < 64) { ls[t] += ls[t + 64]; lq[t] += lq[t + 64]; }
    __syncthreads();
    if (t < 32) {
        float* rep = statsR + (blockIdx.x & 7) * 64;
        atomicAdd(&rep[t], ls[t] + ls[t + 32]);
        atomicAdd(&rep[32 + t], lq[t] + lq[t + 32]);
    }
}

// ---- final BN + prediction dot -> vbuf; init out with pred_b. ----
__global__ __launch_bounds__(256) void bn_norm_final(
    const float* __restrict__ obuf, const float* __restrict__ statsR,
    const float* __restrict__ g, const float* __restrict__ b,
    float* __restrict__ vbuf, const float* __restrict__ predW,
    float* __restrict__ out, const float* __restrict__ pred_b)
{
    int idx = blockIdx.x * 256 + threadIdx.x;
    if (idx < kG) out[idx] = pred_b[0];
    if (idx >= kN * 32) return;
    int c = idx & 31;
    float sum = 0.f, sq = 0.f;
    #pragma unroll
    for (int r = 0; r < 8; ++r) {
        sum += statsR[r * 64 + c];
        sq  += statsR[r * 64 + 32 + c];
    }
    float mu = sum * (1.f / kN);
    float var = sq * (1.f / kN) - mu * mu;
    float inv = rsqrtf(var + kEps);
    float v = (obuf[idx] - mu) * inv * g[c] + b[c];
    float pv = v * predW[c];
    #pragma unroll
    for (int off = 16; off > 0; off >>= 1) pv += __shfl_down(pv, off, 32);
    if (c == 0) vbuf[idx >> 5] = pv;
}

// ---- segment readout over sorted batch ids. ----
__global__ __launch_bounds__(256) void seg_readout(
    const float* __restrict__ vbuf, const int* __restrict__ batch,
    float* __restrict__ out)
{
    __shared__ float ls[kG];
    int t = threadIdx.x;
    for (int i = t; i < kG; i += 256) ls[i] = 0.f;
    __syncthreads();
    int base = blockIdx.x * 2048 + t * 8;
    int cur = -1; float acc = 0.f;
    #pragma unroll
    for (int i = 0; i < 8; ++i) {
        int n = base + i;
        if (n >= kN) break;
        int gi = batch[n];
        float val = vbuf[n];
        if (gi != cur) {
            if (cur >= 0) atomicAdd(&ls[cur], acc);
            cur = gi; acc = val;
        } else acc += val;
    }
    if (cur >= 0) atomicAdd(&ls[cur], acc);
    __syncthreads();
    for (int i = t; i < kG; i += 256) {
        float s = ls[i];
        if (s != 0.f) atomicAdd(&out[i], s);
    }
}

} // namespace

extern "C" void kernel_launch(void* const* d_in, const int* in_sizes, int n_in,
                              void* d_out, int out_size, void* d_ws, size_t ws_size,
                              hipStream_t stream)
{
    const float* x      = (const float*)d_in[0];
    const int*   ei     = (const int*)d_in[1];
    const float* ea     = (const float*)d_in[2];
    const int*   batch  = (const int*)d_in[3];
    const float* lin_W  = (const float*)d_in[4];
    const float* lin_b  = (const float*)d_in[5];
    const float* mes_W1 = (const float*)d_in[6];
    const float* mes_b1 = (const float*)d_in[7];
    const float* mes_W2 = (const float*)d_in[8];
    const float* mes_b2 = (const float*)d_in[9];
    const float* root_W = (const float*)d_in[10];
    const float* conv_b = (const float*)d_in[11];
    const float* bn_g   = (const float*)d_in[12];
    const float* bn_b   = (const float*)d_in[13];
    const float* pred_W = (const float*)d_in[14];
    const float* pred_b = (const float*)d_in[15];
    float* out = (float*)d_out;

    // ws: stats[1536 f, 8KB pad] | deg[N] cursor[N] blkSum[256] blkOff[256]
    //     | hbuf[N*32 f] | obuf[N*32 f] | Y[N*256 us] | hq[3*E uint4]
    // vbuf[N f] overlays Y (dead after last edge_scat).
    char* wsb = (char*)d_ws;
    float* stats = (float*)wsb;
    int* deg     = (int*)(wsb + 8192);
    int* cursor  = deg + kN;
    int* blkSum  = cursor + kN;
    int* blkOff  = blkSum + 256;
    float* hbuf  = (float*)(blkOff + 256);
    float* obuf  = hbuf + (size_t)kN * 32;
    unsigned short* Yus = (unsigned short*)(obuf + (size_t)kN * 32);
    unsigned* Ydw = (unsigned*)Yus;
    uint4* hq    = (uint4*)(Yus + (size_t)kN * 256);
    float* vbuf  = (float*)Yus;

    zero_init<<<kNB, 256, 0, stream>>>(deg, stats);
    deg_hist<<<kEB, 256, 0, stream>>>(ei, deg);
    init_h<<<kNB, 1024, 0, stream>>>(x, lin_W, lin_b, hbuf);
    scan_part<<<kNB, 256, 0, stream>>>(deg, blkSum);
    scan_top<<<1, 256, 0, stream>>>(blkSum, blkOff);
    scan_add<<<kNB, 256, 0, stream>>>(deg, blkOff, cursor);
    hid_pre<<<kEB, 256, 0, stream>>>(ea, mes_W1, mes_b1, ei, cursor, hq);

    int scatBlocks = ((kE / 16) * 32 + 255) / 256;   // 12500 groups
    for (int l = 0; l < 3; ++l) {
        y_root<<<kNB, 1024, 0, stream>>>(
            hbuf, obuf, mes_W2 + (size_t)l * 5120, mes_b2 + (size_t)l * 1024,
            root_W + (size_t)l * 1024, conv_b + l * 32,
            stats + (l ? (l - 1) * 512 : 0),
            bn_g + (l ? (l - 1) * 32 : 0), bn_b + (l ? (l - 1) * 32 : 0),
            l == 0 ? 1 : 0, Ydw);
        edge_scat<<<scatBlocks, 256, 0, stream>>>(
            hq + (size_t)l * kE, Yus, obuf);
        bn_reduce<<<512, 256, 0, stream>>>(obuf, stats + l * 512);
    }

    bn_norm_final<<<(kN * 32 + 255) / 256, 256, 0, stream>>>(
        obuf, stats + 2 * 512, bn_g + 64, bn_b + 64, vbuf, pred_W, out, pred_b);
    seg_readout<<<(kN + 2047) / 2048, 256, 0, stream>>>(vbuf, batch, out);
}